// Round 5
// baseline (267.081 us; speedup 1.0000x reference)
//
#include <hip/hip_runtime.h>
#include <hip/hip_bf16.h>

#define S_ 2048
#define D_ 64
#define BM 64           // q rows per block (4 waves x 16)
#define BN 128          // key tile
#define VSTR 136        // Vt [d][key] row stride (ushort): 272B, 16B-aligned

typedef __attribute__((ext_vector_type(8))) short bf16x8;   // MFMA A/B frag
typedef __attribute__((ext_vector_type(4))) float f32x4;    // MFMA C/D frag

// half-up bf16 round: differs from RNE only on exact ties (prob 2^-16) — 2 ops
__device__ __forceinline__ unsigned int bfbits(float f) {
    union { float f; unsigned int i; } x; x.f = f;
    return x.i + 0x8000u;
}
__device__ __forceinline__ unsigned int pk2(float lo, float hi) {
    return (bfbits(hi) & 0xffff0000u) | (bfbits(lo) >> 16);
}

// ---- fused prep: K fp32->bf16 [b][s][d]; V fp32 [b][s][d] -> bf16 V^T [b][d][s] ----
__global__ __launch_bounds__(256) void prep(const float* __restrict__ k,
                                            const float* __restrict__ v,
                                            ushort* __restrict__ kbf,
                                            ushort* __restrict__ vtb) {
    __shared__ float Lf[64 * 68];
    const int batch = blockIdx.x >> 5;
    const int kt    = (blockIdx.x & 31) * 64;
    const int t     = threadIdx.x;

    const float* kb = k + (size_t)batch * S_ * D_ + (size_t)kt * D_;
    ushort*      ko = kbf + (size_t)batch * S_ * D_ + (size_t)kt * D_;
#pragma unroll
    for (int p = 0; p < 2; ++p) {
        const int c = p * 256 + t;
        const float4 a = *(const float4*)(kb + c * 8);
        const float4 b = *(const float4*)(kb + c * 8 + 4);
        uint4 o;
        o.x = pk2(a.x, a.y); o.y = pk2(a.z, a.w);
        o.z = pk2(b.x, b.y); o.w = pk2(b.z, b.w);
        *(uint4*)(ko + c * 8) = o;
    }

    const float* vb = v + (size_t)batch * S_ * D_ + (size_t)kt * D_;
#pragma unroll
    for (int p = 0; p < 4; ++p) {
        const int c   = p * 256 + t;
        const int key = c >> 4, dp = c & 15;
        *(float4*)(&Lf[key * 68 + dp * 4]) = *(const float4*)(vb + key * 64 + dp * 4);
    }
    __syncthreads();
    const int d = t >> 2, kg = t & 3;
    float x[16];
#pragma unroll
    for (int j = 0; j < 16; ++j) x[j] = Lf[(kg * 16 + j) * 68 + d];
    uint4 o0, o1;
    o0.x = pk2(x[0], x[1]);  o0.y = pk2(x[2], x[3]);
    o0.z = pk2(x[4], x[5]);  o0.w = pk2(x[6], x[7]);
    o1.x = pk2(x[8], x[9]);  o1.y = pk2(x[10], x[11]);
    o1.z = pk2(x[12], x[13]); o1.w = pk2(x[14], x[15]);
    ushort* ob = vtb + (size_t)batch * D_ * S_ + (size_t)d * S_ + kt + kg * 16;
    *(uint4*)(ob)     = o0;
    *(uint4*)(ob + 8) = o1;
}

// ---- flash attention, S^T formulation; K A-frags direct from global (VMEM pipe),
//      V A-frags via LDS. LDS traffic halved vs R4. ----
__global__ __launch_bounds__(256, 4) void fattn(const float* __restrict__ q,
                                                const ushort* __restrict__ kbf,
                                                const ushort* __restrict__ vtb_g,
                                                float* __restrict__ out) {
    __shared__ ushort Vt[D_ * VSTR];     // [d][key] bf16, 17.4 KB

    const int tid  = threadIdx.x;
    const int wid  = tid >> 6;
    const int lane = tid & 63;
    const int ln   = lane & 15;
    const int quad = lane >> 4;

    const int batch = blockIdx.x >> 5;
    const int qtile = blockIdx.x & 31;

    const float*  qp  = q     + (size_t)batch * S_ * D_;
    const ushort* kp  = kbf   + (size_t)batch * S_ * D_;
    const ushort* vtb = vtb_g + (size_t)batch * D_ * S_;

    // staging decomposition for V tile: 1024 16B chunks, 4 per thread
    const int sc_d    = tid >> 4;            // base d row (chunks c = p*256+tid -> d = c>>4)
    const int sc_part = tid & 15;

    // ---- persistent Q B-frags, pre-scaled by log2(e)/sqrt(64) ----
    const float SC = 0.18033688011112042f;
    const int qr0 = qtile * BM + wid * 16;
    union { bf16x8 v; unsigned int u[4]; } uq0, uq1;
    {
        const float* qrow = qp + (size_t)(qr0 + ln) * D_ + quad * 8;
#pragma unroll
        for (int j = 0; j < 4; ++j) {
            uq0.u[j] = pk2(qrow[2 * j] * SC,      qrow[2 * j + 1] * SC);
            uq1.u[j] = pk2(qrow[32 + 2 * j] * SC, qrow[32 + 2 * j + 1] * SC);
        }
    }
    const bf16x8 qf0 = uq0.v, qf1 = uq1.v;

    const f32x4 zero4 = {0.f, 0.f, 0.f, 0.f};
    f32x4 O[4];                      // O^T accum: row d=mt*16+quad*4+r, col q=ln
#pragma unroll
    for (int mt = 0; mt < 4; ++mt) O[mt] = zero4;
    float m = -INFINITY, l = 0.f;

    // ---- prefetch V tile 0 into registers ----
    uint4 vstage[4];
#pragma unroll
    for (int p = 0; p < 4; ++p) {
        const int d = sc_d + p * 16;
        vstage[p] = *(const uint4*)(vtb + (size_t)d * S_ + 0 + sc_part * 8);
    }

    for (int kt = 0; kt < S_; kt += BN) {
        __syncthreads();             // prev tile's readers done
        // ---- write prefetched V tile to LDS ----
#pragma unroll
        for (int p = 0; p < 4; ++p) {
            const int d = sc_d + p * 16;
            *(uint4*)(&Vt[d * VSTR + sc_part * 8]) = vstage[p];
        }
        // ---- prefetch next V tile (latency overlaps compute below) ----
        if (kt + BN < S_) {
#pragma unroll
            for (int p = 0; p < 4; ++p) {
                const int d = sc_d + p * 16;
                vstage[p] = *(const uint4*)(vtb + (size_t)d * S_ + (kt + BN) + sc_part * 8);
            }
        }
        __syncthreads();

        // ---- S^T = K Q^T : K A-frags straight from global (L2-resident) ----
        f32x4 sa[8];
        const ushort* kbase = kp + (size_t)kt * D_ + (size_t)ln * D_ + quad * 8;
#pragma unroll
        for (int mt = 0; mt < 8; ++mt) {
            const ushort* kr = kbase + mt * 16 * D_;
            const bf16x8 k0 = *(const bf16x8*)(kr);
            const bf16x8 k1 = *(const bf16x8*)(kr + 32);
            f32x4 acc = __builtin_amdgcn_mfma_f32_16x16x32_bf16(k0, qf0, zero4, 0, 0, 0);
            sa[mt]    = __builtin_amdgcn_mfma_f32_16x16x32_bf16(k1, qf1, acc, 0, 0, 0);
        }

        // ---- online softmax: in-lane tree + 2 cross-quad shuffles ----
        f32x4 t0 = sa[0], t1 = sa[4];
#pragma unroll
        for (int mt = 1; mt < 4; ++mt) {
#pragma unroll
            for (int j = 0; j < 4; ++j) {
                t0[j] = fmaxf(t0[j], sa[mt][j]);
                t1[j] = fmaxf(t1[j], sa[mt + 4][j]);
            }
        }
        float tm = fmaxf(fmaxf(fmaxf(t0[0], t0[1]), fmaxf(t0[2], t0[3])),
                         fmaxf(fmaxf(t1[0], t1[1]), fmaxf(t1[2], t1[3])));
        tm = fmaxf(tm, __shfl_xor(tm, 16));
        tm = fmaxf(tm, __shfl_xor(tm, 32));
        const float mnew = fmaxf(m, tm);
        const float alpha = exp2f(m - mnew);
#pragma unroll
        for (int mt = 0; mt < 8; ++mt)
#pragma unroll
            for (int j = 0; j < 4; ++j) sa[mt][j] = exp2f(sa[mt][j] - mnew);
        f32x4 s0 = sa[0] + sa[1] + sa[2] + sa[3];
        f32x4 s1 = sa[4] + sa[5] + sa[6] + sa[7];
        s0 += s1;
        float rs = (s0[0] + s0[1]) + (s0[2] + s0[3]);
        rs += __shfl_xor(rs, 16);
        rs += __shfl_xor(rs, 32);
        l = l * alpha + rs;
        m = mnew;
#pragma unroll
        for (int mt = 0; mt < 4; ++mt) O[mt] *= alpha;

        // ---- O^T += V^T P^T (k-permuted; B-frag = own sa regs packed) ----
#pragma unroll
        for (int f = 0; f < 4; ++f) {
            union { bf16x8 v; unsigned int u[4]; } pf;
            pf.u[0] = pk2(sa[2 * f][0],     sa[2 * f][1]);
            pf.u[1] = pk2(sa[2 * f][2],     sa[2 * f][3]);
            pf.u[2] = pk2(sa[2 * f + 1][0], sa[2 * f + 1][1]);
            pf.u[3] = pk2(sa[2 * f + 1][2], sa[2 * f + 1][3]);
#pragma unroll
            for (int mt = 0; mt < 4; ++mt) {
                const ushort* vbase = &Vt[(mt * 16 + ln) * VSTR + quad * 4 + f * 32];
                union { bf16x8 v; uint2 p[2]; } vf;
                vf.p[0] = *(const uint2*)(vbase);        // keys f*32+quad*4+0..3
                vf.p[1] = *(const uint2*)(vbase + 16);   // keys f*32+16+quad*4+0..3
                O[mt] = __builtin_amdgcn_mfma_f32_16x16x32_bf16(vf.v, pf.v, O[mt], 0, 0, 0);
            }
        }
    }

    // ---- epilogue: out[q][d] = O^T[d][q] / l ; float4 per tile ----
    const float linv = 1.0f / l;
    float* op = out + (size_t)batch * S_ * D_ + (size_t)(qr0 + ln) * D_ + quad * 4;
#pragma unroll
    for (int mt = 0; mt < 4; ++mt) {
        float4 st;
        st.x = O[mt][0] * linv; st.y = O[mt][1] * linv;
        st.z = O[mt][2] * linv; st.w = O[mt][3] * linv;
        *(float4*)(op + mt * 16) = st;
    }
}

extern "C" void kernel_launch(void* const* d_in, const int* in_sizes, int n_in,
                              void* d_out, int out_size, void* d_ws, size_t ws_size,
                              hipStream_t stream) {
    const float* q = (const float*)d_in[0];
    const float* k = (const float*)d_in[1];
    const float* v = (const float*)d_in[2];
    float* o = (float*)d_out;

    ushort* kbf = (ushort*)d_ws;                       // 8 MB bf16 K [b][s][d]
    ushort* vtb = kbf + (size_t)32 * S_ * D_;          // 8 MB bf16 V^T [b][d][s]

    prep<<<dim3(1024), dim3(256), 0, stream>>>(k, v, kbf, vtb);
    fattn<<<dim3(1024), dim3(256), 0, stream>>>(q, kbf, vtb, o);
}

// Round 6
// 218.921 us; speedup vs baseline: 1.2200x; 1.2200x over previous
//
#include <hip/hip_runtime.h>
#include <hip/hip_bf16.h>

#define S_ 2048
#define D_ 64
#define BM 64           // q rows per block (4 waves x 16)
#define BN 128          // key tile
#define VSTR 136        // Vt [d][key] row stride (ushort): 272B, 16B-aligned

typedef __attribute__((ext_vector_type(8))) short bf16x8;   // MFMA A/B frag
typedef __attribute__((ext_vector_type(4))) float f32x4;    // MFMA C/D frag

// half-up bf16 round: differs from RNE only on exact ties (prob 2^-16) — 2 ops
__device__ __forceinline__ unsigned int bfbits(float f) {
    union { float f; unsigned int i; } x; x.f = f;
    return x.i + 0x8000u;
}
__device__ __forceinline__ unsigned int pk2(float lo, float hi) {
    return (bfbits(hi) & 0xffff0000u) | (bfbits(lo) >> 16);
}

// ---- fused prep: K fp32->bf16 [b][s][d]; V fp32 [b][s][d] -> bf16 V^T [b][d][s] ----
__global__ __launch_bounds__(256) void prep(const float* __restrict__ k,
                                            const float* __restrict__ v,
                                            ushort* __restrict__ kbf,
                                            ushort* __restrict__ vtb) {
    __shared__ float Lf[64 * 68];
    const int batch = blockIdx.x >> 5;
    const int kt    = (blockIdx.x & 31) * 64;
    const int t     = threadIdx.x;

    const float* kb = k + (size_t)batch * S_ * D_ + (size_t)kt * D_;
    ushort*      ko = kbf + (size_t)batch * S_ * D_ + (size_t)kt * D_;
#pragma unroll
    for (int p = 0; p < 2; ++p) {
        const int c = p * 256 + t;
        const float4 a = *(const float4*)(kb + c * 8);
        const float4 b = *(const float4*)(kb + c * 8 + 4);
        uint4 o;
        o.x = pk2(a.x, a.y); o.y = pk2(a.z, a.w);
        o.z = pk2(b.x, b.y); o.w = pk2(b.z, b.w);
        *(uint4*)(ko + c * 8) = o;
    }

    const float* vb = v + (size_t)batch * S_ * D_ + (size_t)kt * D_;
#pragma unroll
    for (int p = 0; p < 4; ++p) {
        const int c   = p * 256 + t;
        const int key = c >> 4, dp = c & 15;
        *(float4*)(&Lf[key * 68 + dp * 4]) = *(const float4*)(vb + key * 64 + dp * 4);
    }
    __syncthreads();
    const int d = t >> 2, kg = t & 3;
    float x[16];
#pragma unroll
    for (int j = 0; j < 16; ++j) x[j] = Lf[(kg * 16 + j) * 68 + d];
    uint4 o0, o1;
    o0.x = pk2(x[0], x[1]);  o0.y = pk2(x[2], x[3]);
    o0.z = pk2(x[4], x[5]);  o0.w = pk2(x[6], x[7]);
    o1.x = pk2(x[8], x[9]);  o1.y = pk2(x[10], x[11]);
    o1.z = pk2(x[12], x[13]); o1.w = pk2(x[14], x[15]);
    ushort* ob = vtb + (size_t)batch * D_ * S_ + (size_t)d * S_ + kt + kg * 16;
    *(uint4*)(ob)     = o0;
    *(uint4*)(ob + 8) = o1;
}

// ---- flash attention, S^T formulation ----
// K A-frags direct from global (VMEM/L2 pipe); V A-frags via LDS (no register
// carry across barriers -> no scratch); Q B-frags persistent in regs.
// launch_bounds(256,3): 168-VGPR cap so the unrolled QK K-frags don't spill.
__global__ __launch_bounds__(256, 3) void fattn(const float* __restrict__ q,
                                                const ushort* __restrict__ kbf,
                                                const ushort* __restrict__ vtb_g,
                                                float* __restrict__ out) {
    __shared__ ushort Vt[D_ * VSTR];     // [d][key] bf16, 17.4 KB

    const int tid  = threadIdx.x;
    const int wid  = tid >> 6;
    const int lane = tid & 63;
    const int ln   = lane & 15;
    const int quad = lane >> 4;

    const int batch = blockIdx.x >> 5;
    const int qtile = blockIdx.x & 31;

    const float*  qp  = q     + (size_t)batch * S_ * D_;
    const ushort* kp  = kbf   + (size_t)batch * S_ * D_;
    const ushort* vtb = vtb_g + (size_t)batch * D_ * S_;

    // V staging decomposition: 1024 16B chunks, 4 per thread
    const int sc_d    = tid >> 4;        // d row base (p*16 added)
    const int sc_part = tid & 15;

    // ---- persistent Q B-frags, pre-scaled by log2(e)/sqrt(64) ----
    const float SC = 0.18033688011112042f;
    const int qr0 = qtile * BM + wid * 16;
    union { bf16x8 v; unsigned int u[4]; } uq0, uq1;
    {
        const float* qrow = qp + (size_t)(qr0 + ln) * D_ + quad * 8;
#pragma unroll
        for (int j = 0; j < 4; ++j) {
            uq0.u[j] = pk2(qrow[2 * j] * SC,      qrow[2 * j + 1] * SC);
            uq1.u[j] = pk2(qrow[32 + 2 * j] * SC, qrow[32 + 2 * j + 1] * SC);
        }
    }
    const bf16x8 qf0 = uq0.v, qf1 = uq1.v;

    const f32x4 zero4 = {0.f, 0.f, 0.f, 0.f};
    f32x4 O[4];                      // O^T accum: row d=mt*16+quad*4+r, col q=ln
#pragma unroll
    for (int mt = 0; mt < 4; ++mt) O[mt] = zero4;
    float m = -INFINITY, l = 0.f;

    for (int kt = 0; kt < S_; kt += BN) {
        __syncthreads();             // prev tile's readers done
        // ---- stage V^T tile [64][128]: straight global->LDS uint4 ----
#pragma unroll
        for (int p = 0; p < 4; ++p) {
            const int d = sc_d + p * 16;
            *(uint4*)(&Vt[d * VSTR + sc_part * 8]) =
                *(const uint4*)(vtb + (size_t)d * S_ + kt + sc_part * 8);
        }
        __syncthreads();

        // ---- S^T = K Q^T : K A-frags straight from global (L2-resident) ----
        f32x4 sa[8];
        const ushort* kbase = kp + (size_t)kt * D_ + (size_t)ln * D_ + quad * 8;
#pragma unroll
        for (int mt = 0; mt < 8; ++mt) {
            const ushort* kr = kbase + mt * 16 * D_;
            const bf16x8 k0 = *(const bf16x8*)(kr);
            const bf16x8 k1 = *(const bf16x8*)(kr + 32);
            f32x4 acc = __builtin_amdgcn_mfma_f32_16x16x32_bf16(k0, qf0, zero4, 0, 0, 0);
            sa[mt]    = __builtin_amdgcn_mfma_f32_16x16x32_bf16(k1, qf1, acc, 0, 0, 0);
        }

        // ---- online softmax: in-lane tree + 2 cross-quad shuffles ----
        f32x4 t0 = sa[0], t1 = sa[4];
#pragma unroll
        for (int mt = 1; mt < 4; ++mt) {
#pragma unroll
            for (int j = 0; j < 4; ++j) {
                t0[j] = fmaxf(t0[j], sa[mt][j]);
                t1[j] = fmaxf(t1[j], sa[mt + 4][j]);
            }
        }
        float tm = fmaxf(fmaxf(fmaxf(t0[0], t0[1]), fmaxf(t0[2], t0[3])),
                         fmaxf(fmaxf(t1[0], t1[1]), fmaxf(t1[2], t1[3])));
        tm = fmaxf(tm, __shfl_xor(tm, 16));
        tm = fmaxf(tm, __shfl_xor(tm, 32));
        const float mnew = fmaxf(m, tm);
        const float alpha = exp2f(m - mnew);
#pragma unroll
        for (int mt = 0; mt < 8; ++mt)
#pragma unroll
            for (int j = 0; j < 4; ++j) sa[mt][j] = exp2f(sa[mt][j] - mnew);
        f32x4 s0 = sa[0] + sa[1] + sa[2] + sa[3];
        f32x4 s1 = sa[4] + sa[5] + sa[6] + sa[7];
        s0 += s1;
        float rs = (s0[0] + s0[1]) + (s0[2] + s0[3]);
        rs += __shfl_xor(rs, 16);
        rs += __shfl_xor(rs, 32);
        l = l * alpha + rs;
        m = mnew;
#pragma unroll
        for (int mt = 0; mt < 4; ++mt) O[mt] *= alpha;

        // ---- O^T += V^T P^T (k-permuted; B-frag = own sa regs packed) ----
#pragma unroll
        for (int f = 0; f < 4; ++f) {
            union { bf16x8 v; unsigned int u[4]; } pf;
            pf.u[0] = pk2(sa[2 * f][0],     sa[2 * f][1]);
            pf.u[1] = pk2(sa[2 * f][2],     sa[2 * f][3]);
            pf.u[2] = pk2(sa[2 * f + 1][0], sa[2 * f + 1][1]);
            pf.u[3] = pk2(sa[2 * f + 1][2], sa[2 * f + 1][3]);
#pragma unroll
            for (int mt = 0; mt < 4; ++mt) {
                const ushort* vbase = &Vt[(mt * 16 + ln) * VSTR + quad * 4 + f * 32];
                union { bf16x8 v; uint2 p[2]; } vf;
                vf.p[0] = *(const uint2*)(vbase);        // keys f*32+quad*4+0..3
                vf.p[1] = *(const uint2*)(vbase + 16);   // keys f*32+16+quad*4+0..3
                O[mt] = __builtin_amdgcn_mfma_f32_16x16x32_bf16(vf.v, pf.v, O[mt], 0, 0, 0);
            }
        }
    }

    // ---- epilogue: out[q][d] = O^T[d][q] / l ; float4 per tile ----
    const float linv = 1.0f / l;
    float* op = out + (size_t)batch * S_ * D_ + (size_t)(qr0 + ln) * D_ + quad * 4;
#pragma unroll
    for (int mt = 0; mt < 4; ++mt) {
        float4 st;
        st.x = O[mt][0] * linv; st.y = O[mt][1] * linv;
        st.z = O[mt][2] * linv; st.w = O[mt][3] * linv;
        *(float4*)(op + mt * 16) = st;
    }
}

extern "C" void kernel_launch(void* const* d_in, const int* in_sizes, int n_in,
                              void* d_out, int out_size, void* d_ws, size_t ws_size,
                              hipStream_t stream) {
    const float* q = (const float*)d_in[0];
    const float* k = (const float*)d_in[1];
    const float* v = (const float*)d_in[2];
    float* o = (float*)d_out;

    ushort* kbf = (ushort*)d_ws;                       // 8 MB bf16 K [b][s][d]
    ushort* vtb = kbf + (size_t)32 * S_ * D_;          // 8 MB bf16 V^T [b][d][s]

    prep<<<dim3(1024), dim3(256), 0, stream>>>(k, v, kbf, vtb);
    fattn<<<dim3(1024), dim3(256), 0, stream>>>(q, kbf, vtb, o);
}

// Round 7
// 154.028 us; speedup vs baseline: 1.7340x; 1.4213x over previous
//
#include <hip/hip_runtime.h>
#include <hip/hip_bf16.h>

#define S_ 2048
#define D_ 64
#define BM 128          // q rows per block (4 waves x 32)
#define BN 128          // key tile
#define KSTR 72         // Kt [key][d] row stride (ushort): 144B, 16B-aligned
#define VSTR 136        // Vt [d][key] row stride (ushort): 272B, 16B-aligned

typedef __attribute__((ext_vector_type(8))) short bf16x8;    // MFMA A/B frag (4 VGPR)
typedef __attribute__((ext_vector_type(16))) float f32x16;   // 32x32 MFMA C/D frag

// half-up bf16 round: differs from RNE only on exact ties (prob 2^-16) — 2 ops
__device__ __forceinline__ unsigned int bfbits(float f) {
    union { float f; unsigned int i; } x; x.f = f;
    return x.i + 0x8000u;
}
__device__ __forceinline__ unsigned int pk2(float lo, float hi) {
    return (bfbits(hi) & 0xffff0000u) | (bfbits(lo) >> 16);
}

// ---- fused prep: K fp32->bf16 [b][s][d]; V fp32 [b][s][d] -> bf16 V^T [b][d][s] ----
__global__ __launch_bounds__(256) void prep(const float* __restrict__ k,
                                            const float* __restrict__ v,
                                            ushort* __restrict__ kbf,
                                            ushort* __restrict__ vtb) {
    __shared__ float Lf[64 * 68];
    const int batch = blockIdx.x >> 5;
    const int kt    = (blockIdx.x & 31) * 64;
    const int t     = threadIdx.x;

    const float* kb = k + (size_t)batch * S_ * D_ + (size_t)kt * D_;
    ushort*      ko = kbf + (size_t)batch * S_ * D_ + (size_t)kt * D_;
#pragma unroll
    for (int p = 0; p < 2; ++p) {
        const int c = p * 256 + t;
        const float4 a = *(const float4*)(kb + c * 8);
        const float4 b = *(const float4*)(kb + c * 8 + 4);
        uint4 o;
        o.x = pk2(a.x, a.y); o.y = pk2(a.z, a.w);
        o.z = pk2(b.x, b.y); o.w = pk2(b.z, b.w);
        *(uint4*)(ko + c * 8) = o;
    }

    const float* vb = v + (size_t)batch * S_ * D_ + (size_t)kt * D_;
#pragma unroll
    for (int p = 0; p < 4; ++p) {
        const int c   = p * 256 + t;
        const int key = c >> 4, dp = c & 15;
        *(float4*)(&Lf[key * 68 + dp * 4]) = *(const float4*)(vb + key * 64 + dp * 4);
    }
    __syncthreads();
    const int d = t >> 2, kg = t & 3;
    float x[16];
#pragma unroll
    for (int j = 0; j < 16; ++j) x[j] = Lf[(kg * 16 + j) * 68 + d];
    uint4 o0, o1;
    o0.x = pk2(x[0], x[1]);  o0.y = pk2(x[2], x[3]);
    o0.z = pk2(x[4], x[5]);  o0.w = pk2(x[6], x[7]);
    o1.x = pk2(x[8], x[9]);  o1.y = pk2(x[10], x[11]);
    o1.z = pk2(x[12], x[13]); o1.w = pk2(x[14], x[15]);
    ushort* ob = vtb + (size_t)batch * D_ * S_ + (size_t)d * S_ + kt + kg * 16;
    *(uint4*)(ob)     = o0;
    *(uint4*)(ob + 8) = o1;
}

// ---- flash attention, S^T formulation, 32x32x16 MFMA ----
// S^T = mfma(A=K, B=Q): C-layout col=q=lane&31, row=key=(reg&3)+8*(reg>>2)+4*(lane>>5).
// PV: O^T += mfma(A=V^T, B=P^T); key permutation per 32-key group g, half h:
//   slots(lane<32)=0..7 <- keys g*32+h*16+{0..3,8..11} = sa[g] regs h*8+0..7
//   slots(lane>=32)=8..15 <- keys +{4..7,12..15}       = sa[g] regs h*8+0..7
// -> B-frag is the lane's own sa regs packed; A-frag = two b64 LDS reads.
__global__ __launch_bounds__(256, 2) void fattn(const float* __restrict__ q,
                                                const ushort* __restrict__ kbf,
                                                const ushort* __restrict__ vtb_g,
                                                float* __restrict__ out) {
    __shared__ ushort Kt[BN * KSTR];     // [key][d] bf16, 18 KB
    __shared__ ushort Vt[D_ * VSTR];     // [d][key] bf16, 17 KB

    const int tid  = threadIdx.x;
    const int wid  = tid >> 6;
    const int lane = tid & 63;
    const int lq   = lane & 31;      // q column / d row / key row index
    const int lh   = lane >> 5;      // lane half -> k-slot group

    const int batch = blockIdx.x >> 4;       // 16 q-tiles of 128 per batch
    const int qtile = blockIdx.x & 15;

    const float*  qp  = q     + (size_t)batch * S_ * D_;
    const ushort* kp  = kbf   + (size_t)batch * S_ * D_;
    const ushort* vtb = vtb_g + (size_t)batch * D_ * S_;

    // ---- persistent Q B-frags (4 kk), pre-scaled by log2(e)/sqrt(64) ----
    const float SC = 0.18033688011112042f;
    const int qrow = qtile * BM + wid * 32 + lq;
    bf16x8 qf[4];
    {
        const float* qr = qp + (size_t)qrow * D_ + 8 * lh;
#pragma unroll
        for (int kk = 0; kk < 4; ++kk) {
            union { bf16x8 v; unsigned int u[4]; } uq;
#pragma unroll
            for (int j = 0; j < 4; ++j)
                uq.u[j] = pk2(qr[kk * 16 + 2 * j] * SC, qr[kk * 16 + 2 * j + 1] * SC);
            qf[kk] = uq.v;
        }
    }

    f32x16 O[2];                     // O^T: d-rows md*32+row(reg,lane), col q=lq
#pragma unroll
    for (int md = 0; md < 2; ++md)
#pragma unroll
        for (int j = 0; j < 16; ++j) O[md][j] = 0.f;
    float m = -INFINITY, l = 0.f;

    for (int kt = 0; kt < S_; kt += BN) {
        __syncthreads();             // prev tile's readers done
        // ---- stage K [128][64] and V^T [64][128]: 1024+1024 uint4 chunks ----
        {
            const ushort* ktile = kp + (size_t)kt * D_;
#pragma unroll
            for (int p = 0; p < 4; ++p) {
                const int c = p * 256 + tid;
                *(uint4*)(&Kt[(c >> 3) * KSTR + (c & 7) * 8]) =
                    *(const uint4*)(ktile + c * 8);
            }
#pragma unroll
            for (int p = 0; p < 4; ++p) {
                const int c = p * 256 + tid;
                const int d = c >> 4, part = c & 15;
                *(uint4*)(&Vt[d * VSTR + part * 8]) =
                    *(const uint4*)(vtb + (size_t)d * S_ + kt + part * 8);
            }
        }
        __syncthreads();

        // ---- S^T = K Q^T : 4 row-tiles of 32 keys, K-dim 64 = 4 x 16 ----
        f32x16 sa[4];
#pragma unroll
        for (int mt = 0; mt < 4; ++mt) {
            const ushort* krow = &Kt[(mt * 32 + lq) * KSTR + 8 * lh];
            f32x16 acc;
#pragma unroll
            for (int j = 0; j < 16; ++j) acc[j] = 0.f;
#pragma unroll
            for (int kk = 0; kk < 4; ++kk) {
                const bf16x8 kf = *(const bf16x8*)(krow + kk * 16);
                acc = __builtin_amdgcn_mfma_f32_32x32x16_bf16(kf, qf[kk], acc, 0, 0, 0);
            }
            sa[mt] = acc;
        }

        // ---- online softmax: in-lane tree + ONE cross-half shuffle ----
        float tm = -INFINITY;
#pragma unroll
        for (int g = 0; g < 4; ++g)
#pragma unroll
            for (int j = 0; j < 16; ++j) tm = fmaxf(tm, sa[g][j]);
        tm = fmaxf(tm, __shfl_xor(tm, 32, 64));
        const float mnew = fmaxf(m, tm);
        const float alpha = exp2f(m - mnew);
        float rs = 0.f;
#pragma unroll
        for (int g = 0; g < 4; ++g)
#pragma unroll
            for (int j = 0; j < 16; ++j) {
                const float e = exp2f(sa[g][j] - mnew);
                sa[g][j] = e;
                rs += e;
            }
        rs += __shfl_xor(rs, 32, 64);
        l = l * alpha + rs;
        m = mnew;
#pragma unroll
        for (int md = 0; md < 2; ++md)
#pragma unroll
            for (int j = 0; j < 16; ++j) O[md][j] *= alpha;

        // ---- O^T += V^T P^T ----
#pragma unroll
        for (int g = 0; g < 4; ++g) {
#pragma unroll
            for (int h = 0; h < 2; ++h) {
                union { bf16x8 v; unsigned int u[4]; } pf;
#pragma unroll
                for (int i = 0; i < 4; ++i)
                    pf.u[i] = pk2(sa[g][h * 8 + 2 * i], sa[g][h * 8 + 2 * i + 1]);
                const int koff = g * 32 + h * 16 + 4 * lh;
#pragma unroll
                for (int md = 0; md < 2; ++md) {
                    const ushort* vb = &Vt[(md * 32 + lq) * VSTR + koff];
                    union { bf16x8 v; uint2 p[2]; } vf;
                    vf.p[0] = *(const uint2*)(vb);       // keys koff+0..3
                    vf.p[1] = *(const uint2*)(vb + 8);   // keys koff+8..11
                    O[md] = __builtin_amdgcn_mfma_f32_32x32x16_bf16(vf.v, pf.v, O[md], 0, 0, 0);
                }
            }
        }
    }

    // ---- epilogue: out[q][d] = O^T[d][q]/l ; float4 per reg-quad ----
    const float linv = 1.0f / l;
    float* op = out + (size_t)batch * S_ * D_ + (size_t)qrow * D_;
#pragma unroll
    for (int md = 0; md < 2; ++md) {
#pragma unroll
        for (int r4 = 0; r4 < 4; ++r4) {
            const int d = md * 32 + r4 * 8 + 4 * lh;
            float4 st;
            st.x = O[md][r4 * 4 + 0] * linv;
            st.y = O[md][r4 * 4 + 1] * linv;
            st.z = O[md][r4 * 4 + 2] * linv;
            st.w = O[md][r4 * 4 + 3] * linv;
            *(float4*)(op + d) = st;
        }
    }
}

extern "C" void kernel_launch(void* const* d_in, const int* in_sizes, int n_in,
                              void* d_out, int out_size, void* d_ws, size_t ws_size,
                              hipStream_t stream) {
    const float* q = (const float*)d_in[0];
    const float* k = (const float*)d_in[1];
    const float* v = (const float*)d_in[2];
    float* o = (float*)d_out;

    ushort* kbf = (ushort*)d_ws;                       // 8 MB bf16 K [b][s][d]
    ushort* vtb = kbf + (size_t)32 * S_ * D_;          // 8 MB bf16 V^T [b][d][s]

    prep<<<dim3(1024), dim3(256), 0, stream>>>(k, v, kbf, vtb);
    // 32 batches * 16 q-tiles of 128 = 512 blocks
    fattn<<<dim3(512), dim3(256), 0, stream>>>(q, kbf, vtb, o);
}